// Round 6
// baseline (371.816 us; speedup 1.0000x reference)
//
#include <hip/hip_runtime.h>

// BahdanauAttention_83476984365343
//
// Reference: score is [B,T,1]; softmax over the size-1 last axis is
// identically 1.0, so  context[b,d] = sum_t keys[b,t,d].
// query/Ws/Wh/W/tanh are all dead code.
//
// B=32, T=4096, D=512. keys = largest input [B,T,D]. Output is FP32
// (verified round 4->5). Input dtype (fp32 vs bf16-packed) sniffed on-device,
// wave-uniformly, from bit patterns.
//
// Structure (round-6): split T into 32 chunks of 128 rows.
//   Kernel 1: grid (32 chunks, 32 batches) = 1024 blocks x 512 thr
//             = 4 blocks/CU, full 32 waves/CU occupancy. Each block streams
//             whole contiguous rows (wave64 x 16B = 1 KiB bursts), fp32
//             accumulates, folds in LDS, writes [B][chunks][D] partials to ws.
//   Kernel 2: folds 32 chunk-partials (2 MiB, L2-resident) -> out fp32.

#define BB 32
#define TT 4096
#define DD 512

__global__ __launch_bounds__(512) void BahdanauAttention_83476984365343_kernel(
    const unsigned int* __restrict__ keys_raw, float* __restrict__ part,
    int chunks, int tc) {
  const int ck = (int)blockIdx.x;    // T-chunk
  const int b = (int)blockIdx.y;     // batch
  const int tid = (int)threadIdx.x;  // 0..511

  // ---- dtype sniff (wave-uniform; every wave reads the same 64 words) ----
  // bf16-packed: bits 14:7 of each uint are the LOW element's bf16 exponent
  // (~[117,129] for N(0,1)). fp32: those are uniform mantissa bits (~16% hit).
  const unsigned int w0 = keys_raw[tid & 63];
  const unsigned int e_lo = (w0 >> 7) & 0xffu;
  const bool plaus = (e_lo >= 100u) && (e_lo <= 140u);
  const bool is_bf16 = (__popcll(__ballot(plaus)) >= 48);

  __shared__ float smem[8][DD];  // 16 KiB; fp32 path uses rows 0..3

  float colsum;  // this thread's column (= tid) after the fold

  if (!is_bf16) {
    // ---- fp32 path: whole rows, 128 float4 per row, 4 rows in flight ----
    const int vec = tid & 127;  // float4 index within the row
    const int rg = tid >> 7;    // 0..3
    const float4* kp = (const float4*)((const float*)keys_raw +
                                       ((size_t)b * TT + (size_t)ck * tc) * DD);
    float a0 = 0.f, a1 = 0.f, a2 = 0.f, a3 = 0.f;
#pragma unroll 4
    for (int t = rg; t < tc; t += 4) {
      float4 v = kp[(size_t)t * (DD / 4) + vec];
      a0 += v.x; a1 += v.y; a2 += v.z; a3 += v.w;
    }
    float* row = &smem[rg][vec * 4];
    row[0] = a0; row[1] = a1; row[2] = a2; row[3] = a3;
    __syncthreads();
    colsum = (smem[0][tid] + smem[1][tid]) + (smem[2][tid] + smem[3][tid]);
  } else {
    // ---- bf16 path: whole rows, 64 uint4 per row, 8 rows in flight ----
    const int vec = tid & 63;  // uint4 index within the row
    const int rg = tid >> 6;   // 0..7
    const uint4* kp = (const uint4*)(keys_raw +
                                     ((size_t)b * TT + (size_t)ck * tc) * DD / 2);
    float a0 = 0.f, a1 = 0.f, a2 = 0.f, a3 = 0.f;
    float a4 = 0.f, a5 = 0.f, a6 = 0.f, a7 = 0.f;
#pragma unroll 4
    for (int t = rg; t < tc; t += 8) {
      uint4 v = kp[(size_t)t * (DD / 8) + vec];
      // little-endian: element 2k is the LOW 16 bits of word k;
      // bf16 value bits are the high 16 of an fp32.
      a0 += __uint_as_float(v.x << 16);
      a1 += __uint_as_float(v.x & 0xffff0000u);
      a2 += __uint_as_float(v.y << 16);
      a3 += __uint_as_float(v.y & 0xffff0000u);
      a4 += __uint_as_float(v.z << 16);
      a5 += __uint_as_float(v.z & 0xffff0000u);
      a6 += __uint_as_float(v.w << 16);
      a7 += __uint_as_float(v.w & 0xffff0000u);
    }
    float* row = &smem[rg][vec * 8];
    row[0] = a0; row[1] = a1; row[2] = a2; row[3] = a3;
    row[4] = a4; row[5] = a5; row[6] = a6; row[7] = a7;
    __syncthreads();
    float s = 0.f;
#pragma unroll
    for (int k = 0; k < 8; ++k) s += smem[k][tid];
    colsum = s;
  }

  // 512 threads each own one column: coalesced fp32 partial write.
  part[((size_t)b * chunks + ck) * DD + tid] = colsum;
}

// Kernel 2: fold per-chunk partials [B][chunks][D] (2 MiB, L2-hot) -> fp32 out.
__global__ __launch_bounds__(256) void bahdanau_finalize_kernel(
    const float* __restrict__ part, float* __restrict__ out, int chunks) {
  const int idx = (int)(blockIdx.x * 256 + threadIdx.x);  // 0..B*D-1
  const int b = idx >> 9;   // / 512
  const int d = idx & 511;  // % 512
  const float* p = part + (size_t)b * (size_t)chunks * DD + d;
  float s = 0.f;
  for (int c = 0; c < chunks; ++c) s += p[(size_t)c * DD];
  out[idx] = s;
}

extern "C" void kernel_launch(void* const* d_in, const int* in_sizes, int n_in,
                              void* d_out, int out_size, void* d_ws, size_t ws_size,
                              hipStream_t stream) {
  // keys is by far the largest input (32*4096*512 elements); locate by size.
  int ki = 0;
  for (int i = 1; i < n_in; ++i) {
    if (in_sizes[i] > in_sizes[ki]) ki = i;
  }
  const unsigned int* keys_raw = (const unsigned int*)d_in[ki];
  float* part = (float*)d_ws;
  float* out = (float*)d_out;

  // 32 chunks -> 2 MiB fp32 partials in ws (ws is ~1 GiB; halve if smaller).
  int chunks = 32;
  while (chunks > 1 &&
         (size_t)BB * (size_t)chunks * (size_t)DD * sizeof(float) > ws_size) {
    chunks >>= 1;
  }
  const int tc = TT / chunks;

  dim3 grid1((unsigned)chunks, (unsigned)BB);
  BahdanauAttention_83476984365343_kernel<<<grid1, 512, 0, stream>>>(
      keys_raw, part, chunks, tc);
  bahdanau_finalize_kernel<<<(BB * DD) / 256, 256, 0, stream>>>(part, out,
                                                                chunks);
}